// Round 12
// baseline (508.731 us; speedup 1.0000x reference)
//
#include <hip/hip_runtime.h>
#include <hip/hip_fp16.h>
#include <math.h>

static constexpr int D = 64;     // hidden dim
static constexpr int F = 128;    // input features
static constexpr float NEG_SLOPE = 0.2f;
static constexpr float LN_EPS = 1e-5f;
static constexpr float LOG2E = 1.44269504088896340736f;
static constexpr int SCAN_B = 1024;  // elements per scan block (256 thr x 4)
static constexpr int NCHUNK = 8;     // dst-range chunks (== NXCD)

// ---- DPP cross-lane reduction helpers (no LDS traffic) ----
template <int CTRL>
__device__ __forceinline__ float dpp_add(float x) {
  int v = __builtin_amdgcn_update_dpp(0, __float_as_int(x), CTRL, 0xF, 0xF, true);
  return x + __int_as_float(v);
}
// sum within each aligned 16-lane group (result replicated in all 16 lanes)
__device__ __forceinline__ float red16(float x) {
  x = dpp_add<0xB1>(x);    // quad_perm [1,0,3,2]  (xor 1)
  x = dpp_add<0x4E>(x);    // quad_perm [2,3,0,1]  (xor 2)
  x = dpp_add<0x141>(x);   // row_half_mirror
  x = dpp_add<0x140>(x);   // row_mirror
  return x;
}
// sum across full 64-lane wave
__device__ __forceinline__ float red64(float x) {
  x = red16(x);
  x += __shfl_xor(x, 16);
  x += __shfl_xor(x, 32);
  return x;
}

// ---- packed fp16 helpers (ROCm header lacks __hmax2; emit VOP3P directly) ----
__device__ __forceinline__ __half2 h2max(__half2 a, __half2 b) {
  int ai = __builtin_bit_cast(int, a), bi = __builtin_bit_cast(int, b), r;
  asm("v_pk_max_f16 %0, %1, %2" : "=v"(r) : "v"(ai), "v"(bi));
  return __builtin_bit_cast(__half2, r);
}

// packed-f16 swizzle-add: exchange within 16-lane groups on the LDS pipe,
// add on the packed-VALU pipe (2 edges per op).
template <int PAT>
__device__ __forceinline__ __half2 h2_swz_add(__half2 x) {
  int xi = __builtin_bit_cast(int, x);
  int yi = __builtin_amdgcn_ds_swizzle(xi, PAT);
  return __hadd2(x, __builtin_bit_cast(__half2, yi));
}
// sum within each aligned 16-lane group, both packed halves independently
__device__ __forceinline__ __half2 red16_h2(__half2 x) {
  x = h2_swz_add<0x041F>(x);   // xor 1
  x = h2_swz_add<0x081F>(x);   // xor 2
  x = h2_swz_add<0x101F>(x);   // xor 4
  x = h2_swz_add<0x201F>(x);   // xor 8
  return x;
}

// ---------------- CSR build ----------------

__global__ __launch_bounds__(256) void k_init_cnt(int* __restrict__ cnt, int N) {
  int i = blockIdx.x * 256 + threadIdx.x;
  if (i < N) cnt[i] = 1;  // self-loop
}

// dst-range partitioned histogram: chunk c = blockIdx%8 -> XCD-local atomics.
__global__ __launch_bounds__(256) void k_hist(const int* __restrict__ dst,
                                              int* __restrict__ cnt, int E, int N) {
  int c = blockIdx.x & (NCHUNK - 1);
  int b0 = (c * N) / NCHUNK, b1 = ((c + 1) * N) / NCHUNK;
  int stride = (gridDim.x / NCHUNK) * 256;
  for (int e = (blockIdx.x >> 3) * 256 + threadIdx.x; e < E; e += stride) {
    int d = dst[e];
    if (d >= b0 && d < b1) atomicAdd(&cnt[d], 1);
  }
}

// Stage A: per-block local exclusive scan (4 elems/thread) + block sum.
__global__ __launch_bounds__(256) void k_scan_local(const int* __restrict__ cnt,
                                                    int* __restrict__ row_ptr,
                                                    int* __restrict__ bsum, int N) {
  __shared__ int ts[256];
  int t = threadIdx.x;
  int base = blockIdx.x * SCAN_B + t * 4;
  int v[4];
  int s = 0;
#pragma unroll
  for (int i = 0; i < 4; ++i) {
    int idx = base + i;
    v[i] = (idx < N) ? cnt[idx] : 0;
    s += v[i];
  }
  ts[t] = s;
  __syncthreads();
#pragma unroll
  for (int off = 1; off < 256; off <<= 1) {
    int x = (t >= off) ? ts[t - off] : 0;
    __syncthreads();
    ts[t] += x;
    __syncthreads();
  }
  int excl = (t == 0) ? 0 : ts[t - 1];
#pragma unroll
  for (int i = 0; i < 4; ++i) {
    int idx = base + i;
    if (idx < N) { row_ptr[idx] = excl; excl += v[i]; }
  }
  if (t == 255) bsum[blockIdx.x] = ts[255];
}

// Stage B: one block scans the block sums (nb <= 256) -> exclusive, total at bsum[nb].
__global__ __launch_bounds__(256) void k_scan_bsum(int* __restrict__ bsum, int nb) {
  __shared__ int sm[256];
  int t = threadIdx.x;
  sm[t] = (t < nb) ? bsum[t] : 0;
  __syncthreads();
#pragma unroll
  for (int off = 1; off < 256; off <<= 1) {
    int x = (t >= off) ? sm[t - off] : 0;
    __syncthreads();
    sm[t] += x;
    __syncthreads();
  }
  if (t < nb) bsum[t] = (t == 0) ? 0 : sm[t - 1];
  if (t == 255) bsum[nb] = sm[255];  // grand total
}

// Stage C merged with cursor/self-loop init: finalize row_ptr, plant self-loop,
// set cursor past it.
__global__ __launch_bounds__(256) void k_scan_add_cursor(int* __restrict__ row_ptr,
                                                         const int* __restrict__ bsum,
                                                         int* __restrict__ cursor,
                                                         int* __restrict__ ssrc,
                                                         int N, int nb) {
  int i = blockIdx.x * 256 + threadIdx.x;
  if (i < N) {
    int p = row_ptr[i] + bsum[i / SCAN_B];
    row_ptr[i] = p;
    ssrc[p] = i;          // self-loop edge first in segment
    cursor[i] = p + 1;
  }
  if (i == N) row_ptr[N] = bsum[nb];
}

// dst-range partitioned scatter: chunk's cursor + ssrc window stay L2-resident
// on one XCD -> writes coalesce into full lines.
__global__ __launch_bounds__(256) void k_scatter(const int* __restrict__ src,
                                                 const int* __restrict__ dst,
                                                 int* __restrict__ cursor,
                                                 int* __restrict__ ssrc, int E, int N) {
  int c = blockIdx.x & (NCHUNK - 1);
  int b0 = (c * N) / NCHUNK, b1 = ((c + 1) * N) / NCHUNK;
  int stride = (gridDim.x / NCHUNK) * 256;
  for (int e = (blockIdx.x >> 3) * 256 + threadIdx.x; e < E; e += stride) {
    int d = dst[e];
    if (d >= b0 && d < b1) {
      int p = atomicAdd(&cursor[d], 1);
      ssrc[p] = src[e];
    }
  }
}

// ---------------- encoder: h = relu(x @ W_enc + b_enc), tiled ----------------

__global__ __launch_bounds__(256) void k_encoder(const float* __restrict__ x,
                                                 const float* __restrict__ W,
                                                 const float* __restrict__ b,
                                                 float* __restrict__ h, int N) {
  __shared__ float xT[F][64];   // 32 KiB, k-major
  __shared__ float Ws[F][64];   // 32 KiB, [k][c]
  int t = threadIdx.x;
  int n0 = blockIdx.x * 64;
  for (int i = t; i < F * D / 4; i += 256)
    ((float4*)&Ws[0][0])[i] = ((const float4*)W)[i];
  {
    int r = t & 63, kq = (t >> 6) * 4;
    int n = n0 + r;
#pragma unroll
    for (int i = 0; i < 8; ++i) {
      int k0 = kq + 16 * i;
      float4 v = (n < N) ? *(const float4*)&x[(size_t)n * F + k0]
                         : make_float4(0.f, 0.f, 0.f, 0.f);
      xT[k0][r] = v.x; xT[k0 + 1][r] = v.y; xT[k0 + 2][r] = v.z; xT[k0 + 3][r] = v.w;
    }
  }
  __syncthreads();
  int c4 = (t & 15) * 4, n4 = (t >> 4) * 4;
  float acc[4][4];
#pragma unroll
  for (int i = 0; i < 4; ++i)
#pragma unroll
    for (int j = 0; j < 4; ++j) acc[i][j] = b[c4 + j];
#pragma unroll 4
  for (int k = 0; k < F; ++k) {
    float4 xv = *(const float4*)&xT[k][n4];
    float4 wv = *(const float4*)&Ws[k][c4];
    const float* xp = (const float*)&xv;
    const float* wp = (const float*)&wv;
#pragma unroll
    for (int i = 0; i < 4; ++i)
#pragma unroll
      for (int j = 0; j < 4; ++j) acc[i][j] = fmaf(xp[i], wp[j], acc[i][j]);
  }
#pragma unroll
  for (int i = 0; i < 4; ++i) {
    int n = n0 + n4 + i;
    if (n < N) {
      float4 o = make_float4(fmaxf(acc[i][0], 0.f), fmaxf(acc[i][1], 0.f),
                             fmaxf(acc[i][2], 0.f), fmaxf(acc[i][3], 0.f));
      *(float4*)&h[(size_t)n * D + c4] = o;
    }
  }
}

// ---------------- per-layer projections: xl(fp16) = h@Wl+bl, xr(f32) = h@Wr+br ----------------

__global__ __launch_bounds__(256) void k_layer_gemm(const float* __restrict__ h,
                                                    const float* __restrict__ Wl,
                                                    const float* __restrict__ bl,
                                                    const float* __restrict__ Wr,
                                                    const float* __restrict__ br,
                                                    ushort* __restrict__ xlh,
                                                    float* __restrict__ xr, int N) {
  __shared__ float hT[D][64];    // 16 KiB, k-major
  __shared__ float Wls[D][64];   // 16 KiB
  __shared__ float Wrs[D][64];   // 16 KiB
  int t = threadIdx.x;
  int n0 = blockIdx.x * 64;
  for (int i = t; i < D * D / 4; i += 256) {
    ((float4*)&Wls[0][0])[i] = ((const float4*)Wl)[i];
    ((float4*)&Wrs[0][0])[i] = ((const float4*)Wr)[i];
  }
  {
    int r = t & 63, kq = (t >> 6) * 4;
    int n = n0 + r;
#pragma unroll
    for (int i = 0; i < 4; ++i) {
      int k0 = kq + 16 * i;
      float4 v = (n < N) ? *(const float4*)&h[(size_t)n * D + k0]
                         : make_float4(0.f, 0.f, 0.f, 0.f);
      hT[k0][r] = v.x; hT[k0 + 1][r] = v.y; hT[k0 + 2][r] = v.z; hT[k0 + 3][r] = v.w;
    }
  }
  __syncthreads();
  int c4 = (t & 15) * 4, n4 = (t >> 4) * 4;
  float aL[4][4], aR[4][4];
#pragma unroll
  for (int i = 0; i < 4; ++i)
#pragma unroll
    for (int j = 0; j < 4; ++j) { aL[i][j] = bl[c4 + j]; aR[i][j] = br[c4 + j]; }
#pragma unroll 4
  for (int k = 0; k < D; ++k) {
    float4 xv = *(const float4*)&hT[k][n4];
    float4 lv = *(const float4*)&Wls[k][c4];
    float4 rv = *(const float4*)&Wrs[k][c4];
    const float* xp = (const float*)&xv;
    const float* lp = (const float*)&lv;
    const float* rp = (const float*)&rv;
#pragma unroll
    for (int i = 0; i < 4; ++i)
#pragma unroll
      for (int j = 0; j < 4; ++j) {
        aL[i][j] = fmaf(xp[i], lp[j], aL[i][j]);
        aR[i][j] = fmaf(xp[i], rp[j], aR[i][j]);
      }
  }
#pragma unroll
  for (int i = 0; i < 4; ++i) {
    int n = n0 + n4 + i;
    if (n < N) {
      ushort4 o;
      o.x = __half_as_ushort(__float2half_rn(aL[i][0]));
      o.y = __half_as_ushort(__float2half_rn(aL[i][1]));
      o.z = __half_as_ushort(__float2half_rn(aL[i][2]));
      o.w = __half_as_ushort(__float2half_rn(aL[i][3]));
      *(ushort4*)&xlh[(size_t)n * D + c4] = o;
      *(float4*)&xr[(size_t)n * D + c4] =
          make_float4(aR[i][0], aR[i][1], aR[i][2], aR[i][3]);
    }
  }
}

// ---------------- edge + softmax + aggregate + LN + ELU ----------------
// One wave per dst node. Edge indices wave-uniform -> SGPRs. Hierarchical
// batches 16/8/4/masked-4. Score path in PACKED fp16 (2 edges per VGPR):
// v_pk_add/max/mul for leaky+dot, ds_swizzle (LDS pipe) + v_pk_add for the
// 16-lane head reduce. Softmax merge stays f32.

template <int B, bool MASK>
__device__ __forceinline__ void edge_batch(const __half* __restrict__ xlh,
                                           const int* __restrict__ ssrc,
                                           int e, int cnt,
                                           __half2 xr2, __half2 a2, __half2 ns2,
                                           int lane, float& m, float& s, float& acc) {
  int sj[B];
#pragma unroll
  for (int g = 0; g < B / 4; ++g) {
    // same-address 16B load (broadcast), then force components into SGPRs
    int4 q = *(const int4*)(ssrc + e + 4 * g);
    sj[4 * g + 0] = __builtin_amdgcn_readfirstlane(q.x);
    sj[4 * g + 1] = __builtin_amdgcn_readfirstlane(q.y);
    sj[4 * g + 2] = __builtin_amdgcn_readfirstlane(q.z);
    sj[4 * g + 3] = __builtin_amdgcn_readfirstlane(q.w);
  }
  if (MASK) {
#pragma unroll
    for (int j = 1; j < B; ++j)
      if (j >= cnt) sj[j] = sj[0];   // duplicate gather -> L1 hit, score masked
  }
  __half xh[B];
#pragma unroll
  for (int j = 0; j < B; ++j) xh[j] = xlh[(size_t)sj[j] * D + lane];
  // pack 2 edges/VGPR; score math on the packed-f16 pipe
  __half2 p2[B / 2];
#pragma unroll
  for (int j = 0; j < B / 2; ++j) {
    __half2 xs2 = __halves2half2(xh[2 * j], xh[2 * j + 1]);
    __half2 v2 = __hadd2(xs2, xr2);
    __half2 lr2 = h2max(v2, __hmul2(v2, ns2));     // leaky, exact for slope<1
    p2[j] = red16_h2(__hmul2(a2, lr2));            // per-head score (log2 dom)
  }
  float p[B], xs[B];
#pragma unroll
  for (int j = 0; j < B / 2; ++j) {
    p[2 * j] = __low2float(p2[j]);
    p[2 * j + 1] = __high2float(p2[j]);
    xs[2 * j] = __half2float(xh[2 * j]);
    xs[2 * j + 1] = __half2float(xh[2 * j + 1]);
  }
  if (MASK) {
#pragma unroll
    for (int j = 0; j < B; ++j)
      if (j >= cnt) p[j] = -INFINITY;   // masked slot contributes 2^(-inf)=0
  }
  float pmax = p[0];
#pragma unroll
  for (int j = 1; j < B; ++j) pmax = fmaxf(pmax, p[j]);
  float mnew = fmaxf(m, pmax);
  float c = __builtin_amdgcn_exp2f(m - mnew);   // first batch: 2^(-inf)=0
  s *= c; acc *= c;
#pragma unroll
  for (int j = 0; j < B; ++j) {
    float w = __builtin_amdgcn_exp2f(p[j] - mnew);
    s += w;
    acc = fmaf(w, xs[j], acc);
  }
  m = mnew;
}

__global__ __launch_bounds__(256) void k_edge_layer(const __half* __restrict__ xlh,
                                                    const float* __restrict__ xr,
                                                    const int* __restrict__ row_ptr,
                                                    const int* __restrict__ ssrc,
                                                    const float* __restrict__ att_l,
                                                    const float* __restrict__ ob_l,
                                                    const float* __restrict__ g_l,
                                                    const float* __restrict__ be_l,
                                                    float* __restrict__ out, int N) {
  int lane = threadIdx.x & 63;
  int wid = threadIdx.x >> 6;
  int wave = blockIdx.x * 4 + wid;
  int nw = gridDim.x * 4;
  __half2 a2 = __float2half2_rn(att_l[lane] * LOG2E);  // exp2 domain
  __half2 ns2 = __float2half2_rn(NEG_SLOPE);
  float ob = ob_l[lane], gam = g_l[lane], bet = be_l[lane];
  for (int i = wave; i < N; i += nw) {
    __half2 xr2 = __float2half2_rn(xr[(size_t)i * D + lane]);
    int e0 = __builtin_amdgcn_readfirstlane(row_ptr[i]);
    int e1 = __builtin_amdgcn_readfirstlane(row_ptr[i + 1]);
    float m = -INFINITY, s = 0.f, acc = 0.f;
    int e = e0;
    for (; e + 16 <= e1; e += 16)
      edge_batch<16, false>(xlh, ssrc, e, 16, xr2, a2, ns2, lane, m, s, acc);
    if (e + 8 <= e1) {
      edge_batch<8, false>(xlh, ssrc, e, 8, xr2, a2, ns2, lane, m, s, acc);
      e += 8;
    }
    if (e + 4 <= e1) {
      edge_batch<4, false>(xlh, ssrc, e, 4, xr2, a2, ns2, lane, m, s, acc);
      e += 4;
    }
    if (e < e1)
      edge_batch<4, true>(xlh, ssrc, e, e1 - e, xr2, a2, ns2, lane, m, s, acc);
    float res = fmaf(acc, __builtin_amdgcn_rcpf(s), ob);
    // LayerNorm across the 64 channels (full wave)
    float mu = red64(res) * (1.f / 64.f);
    float dv = res - mu;
    float var = red64(dv * dv) * (1.f / 64.f);
    float hn = dv * rsqrtf(var + LN_EPS) * gam + bet;
    out[(size_t)i * D + lane] = hn > 0.f ? hn : expm1f(hn);
  }
}

// ---------------- launch ----------------

extern "C" void kernel_launch(void* const* d_in, const int* in_sizes, int n_in,
                              void* d_out, int out_size, void* d_ws, size_t ws_size,
                              hipStream_t stream) {
  const float* x      = (const float*)d_in[0];
  const int*   ei     = (const int*)d_in[1];
  const float* W_enc  = (const float*)d_in[2];
  const float* b_enc  = (const float*)d_in[3];
  const float* Wl     = (const float*)d_in[4];
  const float* bl     = (const float*)d_in[5];
  const float* Wr     = (const float*)d_in[6];
  const float* br     = (const float*)d_in[7];
  const float* att    = (const float*)d_in[8];
  const float* obias  = (const float*)d_in[9];
  const float* gamma  = (const float*)d_in[10];
  const float* beta   = (const float*)d_in[11];

  int N = in_sizes[0] / F;       // 100000
  int E = in_sizes[1] / 2;       // 1600000
  const int* src = ei;
  const int* dst = ei + E;

  auto align = [](size_t v) { return (v + 255) & ~(size_t)255; };
  char* ws = (char*)d_ws;
  float* h  = (float*)ws;   ws += align((size_t)N * D * 4);
  ushort* xlh = (ushort*)ws; ws += align((size_t)N * D * 2);
  float* xr = (float*)ws;   ws += align((size_t)N * D * 4);
  int* row_ptr = (int*)ws;  ws += align((size_t)(N + 1) * 4);
  int* cursor  = (int*)ws;  ws += align((size_t)N * 4);       // also used as cnt
  int* ssrc    = (int*)ws;  ws += align((size_t)(N + E) * 4);
  int* bsum    = (int*)ws;  ws += align((size_t)1024 * 4);    // also tail-read pad for ssrc

  int nblk = (N + 255) / 256;
  int tblk = (N + 63) / 64;
  int nb = (N + SCAN_B - 1) / SCAN_B;   // 98 for N=100000 (must be <= 256)

  // CSR build (counting sort by dst; self-loop first in each segment)
  k_init_cnt<<<nblk, 256, 0, stream>>>(cursor, N);
  k_hist<<<2048, 256, 0, stream>>>(dst, cursor, E, N);
  k_scan_local<<<nb, 256, 0, stream>>>(cursor, row_ptr, bsum, N);
  k_scan_bsum<<<1, 256, 0, stream>>>(bsum, nb);
  k_scan_add_cursor<<<(N + 256) / 256, 256, 0, stream>>>(row_ptr, bsum, cursor, ssrc, N, nb);
  k_scatter<<<2048, 256, 0, stream>>>(src, dst, cursor, ssrc, E, N);

  // encoder
  k_encoder<<<tblk, 256, 0, stream>>>(x, W_enc, b_enc, h, N);

  for (int l = 0; l < 3; ++l) {
    k_layer_gemm<<<tblk, 256, 0, stream>>>(h, Wl + l * D * D, bl + l * D,
                                           Wr + l * D * D, br + l * D, xlh, xr, N);
    float* out = (l == 2) ? (float*)d_out : h;
    k_edge_layer<<<2048, 256, 0, stream>>>((const __half*)xlh, xr, row_ptr, ssrc,
                                           att + l * 64, obias + l * 64,
                                           gamma + l * 64, beta + l * 64, out, N);
  }
}